// Round 12
// baseline (689.011 us; speedup 1.0000x reference)
//
#include <hip/hip_runtime.h>
#include <hip/hip_bf16.h>

#define ENC_DIM 2048
#define DEC_DIM 512
#define ATT_DIM 512
#define NB 256
#define NP 196
#define M_TOT (NB * NP)   // 50176 = 784 * 64
#define BM 64
#define BK 32
#define NSTEP (ENC_DIM / BK)  // 64

typedef __attribute__((ext_vector_type(8))) short short8;
typedef __attribute__((ext_vector_type(4))) float f32x4;

__device__ __forceinline__ short8 cvt8v(f32x4 x, f32x4 y) {
    union { short8 v; __hip_bfloat16 h[8]; } u;
    u.h[0] = __float2bfloat16(x[0]);
    u.h[1] = __float2bfloat16(x[1]);
    u.h[2] = __float2bfloat16(x[2]);
    u.h[3] = __float2bfloat16(x[3]);
    u.h[4] = __float2bfloat16(y[0]);
    u.h[5] = __float2bfloat16(y[1]);
    u.h[6] = __float2bfloat16(y[2]);
    u.h[7] = __float2bfloat16(y[3]);
    return u.v;
}

// ---------------------------------------------------------------------------
// Kernel 1 (fused): blocks [0,512): pack W_enc into Btt tiled:
//   short-offset = s*16384 + fr*512 + kg*128 + l15*8 holds
//   bf16 W[k = s*32+kg*8 .. +8][col = fr*16+l15]
// => B fragment fr of K-step s is one contiguous 1KB wave load from L2.
// blocks [512,768): att2f = dec@W_dec + b_dec + b_enc.
// ---------------------------------------------------------------------------
__global__ __launch_bounds__(256) void prep_kernel(const float* __restrict__ W,
                                                   __hip_bfloat16* __restrict__ Btt,
                                                   const float* __restrict__ dec,
                                                   const float* __restrict__ W_dec,
                                                   const float* __restrict__ b_dec,
                                                   const float* __restrict__ b_enc,
                                                   float* __restrict__ att2f) {
    __shared__ float ds[DEC_DIM];
    if (blockIdx.x < 512) {
        const int gid = blockIdx.x * 256 + threadIdx.x;  // 0..131071
        const int s   = gid >> 11;        // K-step 0..63
        const int u   = gid & 2047;       // unit within step
        const int fr  = u >> 6;           // col block 0..31
        const int kg  = (u >> 4) & 3;
        const int l15 = u & 15;
        const int col = fr * 16 + l15;
        const int k0  = s * 32 + kg * 8;
        union { short8 v; __hip_bfloat16 h[8]; } x;
        #pragma unroll
        for (int i = 0; i < 8; ++i)
            x.h[i] = __float2bfloat16(W[(size_t)(k0 + i) * ATT_DIM + col]);
        *(short8*)((short*)Btt + (size_t)gid * 8) = x.v;
    } else {
        const int b = blockIdx.x - 512;
        const int t = threadIdx.x;
        ds[t]       = dec[(size_t)b * DEC_DIM + t];
        ds[t + 256] = dec[(size_t)b * DEC_DIM + t + 256];
        __syncthreads();
        #pragma unroll
        for (int j = 0; j < 2; ++j) {
            const int n = t + j * 256;
            float s = 0.f;
            #pragma unroll 8
            for (int k = 0; k < DEC_DIM; ++k)
                s += ds[k] * W_dec[(size_t)k * ATT_DIM + n];
            att2f[(size_t)b * ATT_DIM + n] = s + b_dec[n] + b_enc[n];
        }
    }
}

// ---------------------------------------------------------------------------
// Kernel 2: e[m] = sum_n relu(enc[m,:]@W_enc[:,n] + att2f[b,n]) * W_att[n]
// BARRIER-FREE / LDS-FREE main loop. BM=64 x BN=512 x BK=32; 8 waves, wave
// tile 64x64. Each wave is self-contained:
//   A: fp32 straight from global (16 rows x 64B contiguous per frag; L1
//      catches the 8-wave reuse), cvt->bf16 in-register.
//   B: L2->register from pre-tiled Btt (contiguous 1KB/wave), NONTEMPORAL
//      so B streaming doesn't evict the A tile from L1.
// Depth-2 register pipeline: consume (c,x) -> MFMA -> refill for step s+2.
// No s_barrier, no LDS in the loop => no pipe serialization points.
// ---------------------------------------------------------------------------
__global__ __launch_bounds__(512, 2) void e_kernel(const float* __restrict__ enc,
                                                   const short* __restrict__ Btt,
                                                   const float* __restrict__ att2f,
                                                   const float* __restrict__ W_att,
                                                   float* __restrict__ e_out) {
    __shared__ float ebuf[8][64];

    const int tid  = threadIdx.x;
    const int lane = tid & 63;
    const int wv   = tid >> 6;   // 0..7 : 64-col slice
    const int l15  = lane & 15;
    const int kg   = lane >> 4;  // 0..3
    const int M0   = blockIdx.x * BM;

    // A: lane covers row M0 + mf*16 + l15, 8 fp32 at k = s*32 + kg*8
    const float* asA = enc + (size_t)(M0 + l15) * ENC_DIM + kg * 8;
    // B frag nf of step s: short-offset s*16384 + (wv*4+nf)*512 + kg*128 + l15*8
    const short* pBb = Btt + wv * 2048 + kg * 128 + l15 * 8;

    f32x4 acc[4][4];
    #pragma unroll
    for (int i = 0; i < 4; ++i)
        #pragma unroll
        for (int j = 0; j < 4; ++j)
            acc[i][j] = (f32x4){0.f, 0.f, 0.f, 0.f};

    short8 c0, c1, c2, c3, n0, n1, n2, n3;                  // B dbuf (bf16)
    f32x4 x00, x01, x10, x11, x20, x21, x30, x31;           // A even (fp32)
    f32x4 y00, y01, y10, y11, y20, y21, y30, y31;           // A odd  (fp32)

#define LOADB(d0, d1, d2, d3, S)                                        \
    {                                                                   \
        const short* p = pBb + (size_t)(S) * 16384;                     \
        d0 = __builtin_nontemporal_load((const short8*)(p));            \
        d1 = __builtin_nontemporal_load((const short8*)(p + 512));      \
        d2 = __builtin_nontemporal_load((const short8*)(p + 1024));     \
        d3 = __builtin_nontemporal_load((const short8*)(p + 1536));     \
    }
#define LOADA(d00, d01, d10, d11, d20, d21, d30, d31, S)                \
    {                                                                   \
        const float* p = asA + (size_t)(S) * 32;                        \
        d00 = *(const f32x4*)(p);          d01 = *(const f32x4*)(p + 4);            \
        d10 = *(const f32x4*)(p + 32768);  d11 = *(const f32x4*)(p + 32768 + 4);    \
        d20 = *(const f32x4*)(p + 65536);  d21 = *(const f32x4*)(p + 65536 + 4);    \
        d30 = *(const f32x4*)(p + 98304);  d31 = *(const f32x4*)(p + 98304 + 4);    \
    }
#define MFMA16(A0, A1, A2, A3, B0, B1, B2, B3)                                       \
    acc[0][0] = __builtin_amdgcn_mfma_f32_16x16x32_bf16(A0, B0, acc[0][0], 0, 0, 0); \
    acc[0][1] = __builtin_amdgcn_mfma_f32_16x16x32_bf16(A0, B1, acc[0][1], 0, 0, 0); \
    acc[0][2] = __builtin_amdgcn_mfma_f32_16x16x32_bf16(A0, B2, acc[0][2], 0, 0, 0); \
    acc[0][3] = __builtin_amdgcn_mfma_f32_16x16x32_bf16(A0, B3, acc[0][3], 0, 0, 0); \
    acc[1][0] = __builtin_amdgcn_mfma_f32_16x16x32_bf16(A1, B0, acc[1][0], 0, 0, 0); \
    acc[1][1] = __builtin_amdgcn_mfma_f32_16x16x32_bf16(A1, B1, acc[1][1], 0, 0, 0); \
    acc[1][2] = __builtin_amdgcn_mfma_f32_16x16x32_bf16(A1, B2, acc[1][2], 0, 0, 0); \
    acc[1][3] = __builtin_amdgcn_mfma_f32_16x16x32_bf16(A1, B3, acc[1][3], 0, 0, 0); \
    acc[2][0] = __builtin_amdgcn_mfma_f32_16x16x32_bf16(A2, B0, acc[2][0], 0, 0, 0); \
    acc[2][1] = __builtin_amdgcn_mfma_f32_16x16x32_bf16(A2, B1, acc[2][1], 0, 0, 0); \
    acc[2][2] = __builtin_amdgcn_mfma_f32_16x16x32_bf16(A2, B2, acc[2][2], 0, 0, 0); \
    acc[2][3] = __builtin_amdgcn_mfma_f32_16x16x32_bf16(A2, B3, acc[2][3], 0, 0, 0); \
    acc[3][0] = __builtin_amdgcn_mfma_f32_16x16x32_bf16(A3, B0, acc[3][0], 0, 0, 0); \
    acc[3][1] = __builtin_amdgcn_mfma_f32_16x16x32_bf16(A3, B1, acc[3][1], 0, 0, 0); \
    acc[3][2] = __builtin_amdgcn_mfma_f32_16x16x32_bf16(A3, B2, acc[3][2], 0, 0, 0); \
    acc[3][3] = __builtin_amdgcn_mfma_f32_16x16x32_bf16(A3, B3, acc[3][3], 0, 0, 0);

    // ---- prologue: steps 0 and 1 in flight ----
    LOADB(c0, c1, c2, c3, 0)
    LOADA(x00, x01, x10, x11, x20, x21, x30, x31, 0)
    LOADB(n0, n1, n2, n3, 1)
    LOADA(y00, y01, y10, y11, y20, y21, y30, y31, 1)

    for (int s = 0; s < NSTEP; s += 2) {
        // ---- even: consume (c, x); refill for s+2 ----
        {
            const short8 a0 = cvt8v(x00, x01);
            const short8 a1 = cvt8v(x10, x11);
            const short8 a2 = cvt8v(x20, x21);
            const short8 a3 = cvt8v(x30, x31);
            __builtin_amdgcn_s_setprio(1);
            MFMA16(a0, a1, a2, a3, c0, c1, c2, c3)
            __builtin_amdgcn_s_setprio(0);
        }
        LOADB(c0, c1, c2, c3, (s + 2) & 63)
        LOADA(x00, x01, x10, x11, x20, x21, x30, x31, (s + 2) & 63)

        // ---- odd: consume (n, y); refill for s+3 ----
        {
            const short8 a0 = cvt8v(y00, y01);
            const short8 a1 = cvt8v(y10, y11);
            const short8 a2 = cvt8v(y20, y21);
            const short8 a3 = cvt8v(y30, y31);
            __builtin_amdgcn_s_setprio(1);
            MFMA16(a0, a1, a2, a3, n0, n1, n2, n3)
            __builtin_amdgcn_s_setprio(0);
        }
        LOADB(n0, n1, n2, n3, (s + 3) & 63)
        LOADA(y00, y01, y10, y11, y20, y21, y30, y31, (s + 3) & 63)
    }
#undef MFMA16
#undef LOADA
#undef LOADB

    // epilogue: + att2, relu, * W_att, reduce over n
    float wat[4];
    #pragma unroll
    for (int nf = 0; nf < 4; ++nf) wat[nf] = W_att[wv * 64 + nf * 16 + l15];

    #pragma unroll
    for (int mf = 0; mf < 4; ++mf) {
        #pragma unroll
        for (int rr = 0; rr < 4; ++rr) {
            const int ml = mf * 16 + kg * 4 + rr;   // local row 0..63
            const int bb = (M0 + ml) / NP;
            const float* arow2 = att2f + (size_t)bb * ATT_DIM + wv * 64 + l15;
            float sv = 0.f;
            #pragma unroll
            for (int nf = 0; nf < 4; ++nf) {
                float v = acc[mf][nf][rr] + arow2[nf * 16];
                sv += fmaxf(v, 0.f) * wat[nf];
            }
            sv += __shfl_xor(sv, 1);
            sv += __shfl_xor(sv, 2);
            sv += __shfl_xor(sv, 4);
            sv += __shfl_xor(sv, 8);
            if (l15 == 0) ebuf[wv][ml] = sv;
        }
    }
    __syncthreads();
    if (tid < 64) {
        float sv = 0.f;
        #pragma unroll
        for (int w = 0; w < 8; ++w) sv += ebuf[w][tid];
        e_out[M0 + tid] = sv;
    }
}

// ---------------------------------------------------------------------------
// Kernel 3: per-batch softmax over 196 pixels + z[b,:] = sum_p alpha[b,p]*enc[b,p,:]
// grid (256, 2): 1024-col chunks, float4/thread, dual accumulators.
// ---------------------------------------------------------------------------
__global__ __launch_bounds__(256) void z_kernel(const float* __restrict__ enc,
                                                const float* __restrict__ e,
                                                float* __restrict__ z,
                                                float* __restrict__ alpha) {
    const int b  = blockIdx.x;
    const int cb = blockIdx.y;
    const int t  = threadIdx.x;
    __shared__ float al[NP];
    __shared__ float red[4];

    float ev = (t < NP) ? e[(size_t)b * NP + t] : -1e30f;
    float m = ev;
    #pragma unroll
    for (int o = 32; o > 0; o >>= 1) m = fmaxf(m, __shfl_xor(m, o));
    if ((t & 63) == 0) red[t >> 6] = m;
    __syncthreads();
    m = fmaxf(fmaxf(red[0], red[1]), fmaxf(red[2], red[3]));
    __syncthreads();
    float ex = (t < NP) ? __expf(ev - m) : 0.f;
    float s = ex;
    #pragma unroll
    for (int o = 32; o > 0; o >>= 1) s += __shfl_xor(s, o);
    if ((t & 63) == 0) red[t >> 6] = s;
    __syncthreads();
    s = red[0] + red[1] + red[2] + red[3];
    const float a = ex * (1.0f / s);
    if (t < NP) {
        al[t] = a;
        if (cb == 0) alpha[(size_t)b * NP + t] = a;
    }
    __syncthreads();

    const int c0 = cb * 1024 + t * 4;
    const float4* ep = (const float4*)(enc + (size_t)b * NP * ENC_DIM + c0);
    float4 z0 = make_float4(0.f, 0.f, 0.f, 0.f);
    float4 z1 = make_float4(0.f, 0.f, 0.f, 0.f);
    #pragma unroll 4
    for (int p = 0; p < NP; p += 2) {
        const float a0 = al[p];
        const float a1 = al[p + 1];
        const float4 v0 = ep[(size_t)p * (ENC_DIM / 4)];
        const float4 v1 = ep[(size_t)(p + 1) * (ENC_DIM / 4)];
        z0.x += a0 * v0.x; z0.y += a0 * v0.y; z0.z += a0 * v0.z; z0.w += a0 * v0.w;
        z1.x += a1 * v1.x; z1.y += a1 * v1.y; z1.z += a1 * v1.z; z1.w += a1 * v1.w;
    }
    z0.x += z1.x; z0.y += z1.y; z0.z += z1.z; z0.w += z1.w;
    *(float4*)(z + (size_t)b * ENC_DIM + c0) = z0;
}

// ---------------------------------------------------------------------------
extern "C" void kernel_launch(void* const* d_in, const int* in_sizes, int n_in,
                              void* d_out, int out_size, void* d_ws, size_t ws_size,
                              hipStream_t stream) {
    const float* enc   = (const float*)d_in[0];  // (256,196,2048)
    const float* dec   = (const float*)d_in[1];  // (256,512)
    const float* W_enc = (const float*)d_in[2];  // (2048,512)
    const float* b_enc = (const float*)d_in[3];  // (512)
    const float* W_dec = (const float*)d_in[4];  // (512,512)
    const float* b_dec = (const float*)d_in[5];  // (512)
    const float* W_att = (const float*)d_in[6];  // (512,1)
    // d_in[7] = b_att: softmax-invariant, unused.

    float* z     = (float*)d_out;                 // 256*2048
    float* alpha = z + (size_t)NB * ENC_DIM;      // 256*196

    char* ws = (char*)d_ws;
    __hip_bfloat16* Btt = (__hip_bfloat16*)ws;                        // 2 MB
    float* att2f        = (float*)(ws + 2 * 1024 * 1024);             // 512 KB
    float* e            = (float*)(ws + 2 * 1024 * 1024 + 512 * 1024);// 200 KB

    prep_kernel<<<768, 256, 0, stream>>>(W_enc, Btt, dec, W_dec, b_dec, b_enc, att2f);
    e_kernel<<<M_TOT / BM, 512, 0, stream>>>(enc, (const short*)Btt, att2f, W_att, e);
    z_kernel<<<dim3(NB, 2), 256, 0, stream>>>(enc, e, z, alpha);
}

// Round 13
// 298.858 us; speedup vs baseline: 2.3055x; 2.3055x over previous
//
#include <hip/hip_runtime.h>
#include <hip/hip_bf16.h>

#define ENC_DIM 2048
#define DEC_DIM 512
#define ATT_DIM 512
#define NB 256
#define NP 196
#define M_TOT (NB * NP)   // 50176 = 784 * 64
#define BM 64
#define BK 32
#define NSTEP (ENC_DIM / BK)  // 64

typedef __attribute__((ext_vector_type(8))) short short8;
typedef __attribute__((ext_vector_type(4))) short short4s;
typedef __attribute__((ext_vector_type(4))) float f32x4;

__device__ __forceinline__ short4s cvt4(f32x4 v) {
    union { short4s s; __hip_bfloat16 h[4]; } u;
    u.h[0] = __float2bfloat16(v[0]);
    u.h[1] = __float2bfloat16(v[1]);
    u.h[2] = __float2bfloat16(v[2]);
    u.h[3] = __float2bfloat16(v[3]);
    return u.s;
}

// ---------------------------------------------------------------------------
// Kernel 1 (fused): blocks [0,512): pack W_enc into Btt tiled:
//   short-offset = s*16384 + fr*512 + kg*128 + l15*8 holds
//   bf16 W[k = s*32+kg*8 .. +8][col = fr*16+l15]
// => B fragment fr of K-step s is one contiguous 1KB wave load from L2.
// blocks [512,768): att2f = dec@W_dec + b_dec + b_enc.
// ---------------------------------------------------------------------------
__global__ __launch_bounds__(256) void prep_kernel(const float* __restrict__ W,
                                                   __hip_bfloat16* __restrict__ Btt,
                                                   const float* __restrict__ dec,
                                                   const float* __restrict__ W_dec,
                                                   const float* __restrict__ b_dec,
                                                   const float* __restrict__ b_enc,
                                                   float* __restrict__ att2f) {
    __shared__ float ds[DEC_DIM];
    if (blockIdx.x < 512) {
        const int gid = blockIdx.x * 256 + threadIdx.x;  // 0..131071
        const int s   = gid >> 11;        // K-step 0..63
        const int u   = gid & 2047;       // unit within step
        const int fr  = u >> 6;           // col block 0..31
        const int kg  = (u >> 4) & 3;
        const int l15 = u & 15;
        const int col = fr * 16 + l15;
        const int k0  = s * 32 + kg * 8;
        union { short8 v; __hip_bfloat16 h[8]; } x;
        #pragma unroll
        for (int i = 0; i < 8; ++i)
            x.h[i] = __float2bfloat16(W[(size_t)(k0 + i) * ATT_DIM + col]);
        *(short8*)((short*)Btt + (size_t)gid * 8) = x.v;
    } else {
        const int b = blockIdx.x - 512;
        const int t = threadIdx.x;
        ds[t]       = dec[(size_t)b * DEC_DIM + t];
        ds[t + 256] = dec[(size_t)b * DEC_DIM + t + 256];
        __syncthreads();
        #pragma unroll
        for (int j = 0; j < 2; ++j) {
            const int n = t + j * 256;
            float s = 0.f;
            #pragma unroll 8
            for (int k = 0; k < DEC_DIM; ++k)
                s += ds[k] * W_dec[(size_t)k * ATT_DIM + n];
            att2f[(size_t)b * ATT_DIM + n] = s + b_dec[n] + b_enc[n];
        }
    }
}

// ---------------------------------------------------------------------------
// Kernel 2: e[m] = sum_n relu(enc[m,:]@W_enc[:,n] + att2f[b,n]) * W_att[n]
// BM=64 x BN=512 x BK=32; 8 waves 1Mx8N, wave tile 64x64.
// r9 structure made register-lean for 2 blocks/CU (the m97 overlap engine):
//   - B single-buffered (c0..c3, 32 regs), loaded at step top; its L2
//     latency is hidden by the co-resident second block, not a dbuf.
//   - ds_read of each A-frag interleaved with its 4 MFMAs (one frag live).
//   - peak regs ~122 <= 128 cap from __launch_bounds__(512,4).
// A: reg-staged fp32 -> bf16 -> LDS dbuf (8 KB), depth-2 (load s+2, write s+1).
// ---------------------------------------------------------------------------
__global__ __launch_bounds__(512, 4) void e_kernel(const float* __restrict__ enc,
                                                   const short* __restrict__ Btt,
                                                   const float* __restrict__ att2f,
                                                   const float* __restrict__ W_att,
                                                   float* __restrict__ e_out) {
    __shared__ __attribute__((aligned(16))) short As[2][2048];  // 2 x 4 KB bf16
    __shared__ float ebuf[8][64];

    const int tid  = threadIdx.x;
    const int lane = tid & 63;
    const int wv   = tid >> 6;   // 0..7 : 64-col slice
    const int l15  = lane & 15;
    const int kg   = lane >> 4;  // 0..3
    const int M0   = blockIdx.x * BM;

    // A staging: thread -> (row = tid>>3, k-quad q = tid&7)
    const int arow = tid >> 3;
    const int aq   = tid & 7;
    const float* asrc = enc + (size_t)(M0 + arow) * ENC_DIM + aq * 4;
    // LDS short index: [mf=row>>4][kg=q>>1][l15=row&15][h=q&1]
    const int awr = (arow >> 4) * 512 + (aq >> 1) * 128 + (arow & 15) * 8 + (aq & 1) * 4;

    // B fragment base: frag nf of step s at short-offset s*16384 + (wv*4+nf)*512 + kg*128 + l15*8
    const short* pBb = Btt + wv * 2048 + kg * 128 + l15 * 8;

    f32x4 acc[4][4];
    #pragma unroll
    for (int i = 0; i < 4; ++i)
        #pragma unroll
        for (int j = 0; j < 4; ++j)
            acc[i][j] = (f32x4){0.f, 0.f, 0.f, 0.f};

    // ---- prologue: A(0) -> As[0]; A(1) -> avP ----
    *(short4s*)&As[0][awr] = cvt4(*(const f32x4*)asrc);
    f32x4 avP = *(const f32x4*)(asrc + BK);
    asm volatile("s_waitcnt lgkmcnt(0)" ::: "memory");
    __builtin_amdgcn_s_barrier();

    const short* Ac = &As[0][0];
    short*       An = &As[1][0];

    for (int s = 0; s < NSTEP; ++s) {
        // B(s) single-buffer loads from L2 + A(s+2) HBM load
        const short* pbs = pBb + (size_t)s * 16384;
        const short8 c0 = *(const short8*)(pbs);
        const short8 c1 = *(const short8*)(pbs + 512);
        const short8 c2 = *(const short8*)(pbs + 1024);
        const short8 c3 = *(const short8*)(pbs + 1536);
        f32x4 avN = *(const f32x4*)(asrc + (size_t)((s + 2) & 63) * BK);
        __builtin_amdgcn_sched_barrier(0);

        __builtin_amdgcn_s_setprio(1);
        {
            const short8 a0 = *(const short8*)&Ac[0 * 512 + lane * 8];
            acc[0][0] = __builtin_amdgcn_mfma_f32_16x16x32_bf16(a0, c0, acc[0][0], 0, 0, 0);
            acc[0][1] = __builtin_amdgcn_mfma_f32_16x16x32_bf16(a0, c1, acc[0][1], 0, 0, 0);
            acc[0][2] = __builtin_amdgcn_mfma_f32_16x16x32_bf16(a0, c2, acc[0][2], 0, 0, 0);
            acc[0][3] = __builtin_amdgcn_mfma_f32_16x16x32_bf16(a0, c3, acc[0][3], 0, 0, 0);
        }
        {
            const short8 a1 = *(const short8*)&Ac[1 * 512 + lane * 8];
            acc[1][0] = __builtin_amdgcn_mfma_f32_16x16x32_bf16(a1, c0, acc[1][0], 0, 0, 0);
            acc[1][1] = __builtin_amdgcn_mfma_f32_16x16x32_bf16(a1, c1, acc[1][1], 0, 0, 0);
            acc[1][2] = __builtin_amdgcn_mfma_f32_16x16x32_bf16(a1, c2, acc[1][2], 0, 0, 0);
            acc[1][3] = __builtin_amdgcn_mfma_f32_16x16x32_bf16(a1, c3, acc[1][3], 0, 0, 0);
        }
        {
            const short8 a2 = *(const short8*)&Ac[2 * 512 + lane * 8];
            acc[2][0] = __builtin_amdgcn_mfma_f32_16x16x32_bf16(a2, c0, acc[2][0], 0, 0, 0);
            acc[2][1] = __builtin_amdgcn_mfma_f32_16x16x32_bf16(a2, c1, acc[2][1], 0, 0, 0);
            acc[2][2] = __builtin_amdgcn_mfma_f32_16x16x32_bf16(a2, c2, acc[2][2], 0, 0, 0);
            acc[2][3] = __builtin_amdgcn_mfma_f32_16x16x32_bf16(a2, c3, acc[2][3], 0, 0, 0);
        }
        {
            const short8 a3 = *(const short8*)&Ac[3 * 512 + lane * 8];
            acc[3][0] = __builtin_amdgcn_mfma_f32_16x16x32_bf16(a3, c0, acc[3][0], 0, 0, 0);
            acc[3][1] = __builtin_amdgcn_mfma_f32_16x16x32_bf16(a3, c1, acc[3][1], 0, 0, 0);
            acc[3][2] = __builtin_amdgcn_mfma_f32_16x16x32_bf16(a3, c2, acc[3][2], 0, 0, 0);
            acc[3][3] = __builtin_amdgcn_mfma_f32_16x16x32_bf16(a3, c3, acc[3][3], 0, 0, 0);
        }
        __builtin_amdgcn_s_setprio(0);

        // A(s+1) into the other LDS buffer (its readers drained at last barrier)
        *(short4s*)&An[awr] = cvt4(avP);
        avP = avN;
        asm volatile("s_waitcnt lgkmcnt(0)" ::: "memory");
        __builtin_amdgcn_s_barrier();
        const short* tmp = Ac; Ac = An; An = (short*)tmp;
    }

    // epilogue: + att2, relu, * W_att, reduce over n
    float wat[4];
    #pragma unroll
    for (int nf = 0; nf < 4; ++nf) wat[nf] = W_att[wv * 64 + nf * 16 + l15];

    #pragma unroll
    for (int mf = 0; mf < 4; ++mf) {
        #pragma unroll
        for (int rr = 0; rr < 4; ++rr) {
            const int ml = mf * 16 + kg * 4 + rr;   // local row 0..63
            const int bb = (M0 + ml) / NP;
            const float* arow2 = att2f + (size_t)bb * ATT_DIM + wv * 64 + l15;
            float sv = 0.f;
            #pragma unroll
            for (int nf = 0; nf < 4; ++nf) {
                float v = acc[mf][nf][rr] + arow2[nf * 16];
                sv += fmaxf(v, 0.f) * wat[nf];
            }
            sv += __shfl_xor(sv, 1);
            sv += __shfl_xor(sv, 2);
            sv += __shfl_xor(sv, 4);
            sv += __shfl_xor(sv, 8);
            if (l15 == 0) ebuf[wv][ml] = sv;
        }
    }
    __syncthreads();
    if (tid < 64) {
        float sv = 0.f;
        #pragma unroll
        for (int w = 0; w < 8; ++w) sv += ebuf[w][tid];
        e_out[M0 + tid] = sv;
    }
}

// ---------------------------------------------------------------------------
// Kernel 3: per-batch softmax over 196 pixels + z[b,:] = sum_p alpha[b,p]*enc[b,p,:]
// grid (256, 2): 1024-col chunks, float4/thread, dual accumulators.
// ---------------------------------------------------------------------------
__global__ __launch_bounds__(256) void z_kernel(const float* __restrict__ enc,
                                                const float* __restrict__ e,
                                                float* __restrict__ z,
                                                float* __restrict__ alpha) {
    const int b  = blockIdx.x;
    const int cb = blockIdx.y;
    const int t  = threadIdx.x;
    __shared__ float al[NP];
    __shared__ float red[4];

    float ev = (t < NP) ? e[(size_t)b * NP + t] : -1e30f;
    float m = ev;
    #pragma unroll
    for (int o = 32; o > 0; o >>= 1) m = fmaxf(m, __shfl_xor(m, o));
    if ((t & 63) == 0) red[t >> 6] = m;
    __syncthreads();
    m = fmaxf(fmaxf(red[0], red[1]), fmaxf(red[2], red[3]));
    __syncthreads();
    float ex = (t < NP) ? __expf(ev - m) : 0.f;
    float s = ex;
    #pragma unroll
    for (int o = 32; o > 0; o >>= 1) s += __shfl_xor(s, o);
    if ((t & 63) == 0) red[t >> 6] = s;
    __syncthreads();
    s = red[0] + red[1] + red[2] + red[3];
    const float a = ex * (1.0f / s);
    if (t < NP) {
        al[t] = a;
        if (cb == 0) alpha[(size_t)b * NP + t] = a;
    }
    __syncthreads();

    const int c0 = cb * 1024 + t * 4;
    const float4* ep = (const float4*)(enc + (size_t)b * NP * ENC_DIM + c0);
    float4 z0 = make_float4(0.f, 0.f, 0.f, 0.f);
    float4 z1 = make_float4(0.f, 0.f, 0.f, 0.f);
    #pragma unroll 4
    for (int p = 0; p < NP; p += 2) {
        const float a0 = al[p];
        const float a1 = al[p + 1];
        const float4 v0 = ep[(size_t)p * (ENC_DIM / 4)];
        const float4 v1 = ep[(size_t)(p + 1) * (ENC_DIM / 4)];
        z0.x += a0 * v0.x; z0.y += a0 * v0.y; z0.z += a0 * v0.z; z0.w += a0 * v0.w;
        z1.x += a1 * v1.x; z1.y += a1 * v1.y; z1.z += a1 * v1.z; z1.w += a1 * v1.w;
    }
    z0.x += z1.x; z0.y += z1.y; z0.z += z1.z; z0.w += z1.w;
    *(float4*)(z + (size_t)b * ENC_DIM + c0) = z0;
}

// ---------------------------------------------------------------------------
extern "C" void kernel_launch(void* const* d_in, const int* in_sizes, int n_in,
                              void* d_out, int out_size, void* d_ws, size_t ws_size,
                              hipStream_t stream) {
    const float* enc   = (const float*)d_in[0];  // (256,196,2048)
    const float* dec   = (const float*)d_in[1];  // (256,512)
    const float* W_enc = (const float*)d_in[2];  // (2048,512)
    const float* b_enc = (const float*)d_in[3];  // (512)
    const float* W_dec = (const float*)d_in[4];  // (512,512)
    const float* b_dec = (const float*)d_in[5];  // (512)
    const float* W_att = (const float*)d_in[6];  // (512,1)
    // d_in[7] = b_att: softmax-invariant, unused.

    float* z     = (float*)d_out;                 // 256*2048
    float* alpha = z + (size_t)NB * ENC_DIM;      // 256*196

    char* ws = (char*)d_ws;
    __hip_bfloat16* Btt = (__hip_bfloat16*)ws;                        // 2 MB
    float* att2f        = (float*)(ws + 2 * 1024 * 1024);             // 512 KB
    float* e            = (float*)(ws + 2 * 1024 * 1024 + 512 * 1024);// 200 KB

    prep_kernel<<<768, 256, 0, stream>>>(W_enc, Btt, dec, W_dec, b_dec, b_enc, att2f);
    e_kernel<<<M_TOT / BM, 512, 0, stream>>>(enc, (const short*)Btt, att2f, W_att, e);
    z_kernel<<<dim3(NB, 2), 256, 0, stream>>>(enc, e, z, alpha);
}